// Round 1
// baseline (571.683 us; speedup 1.0000x reference)
//
#include <hip/hip_runtime.h>

#define NEG_SLOPE 0.2f

__device__ __forceinline__ float lrelu(float x){ return x >= 0.0f ? x : NEG_SLOPE * x; }
__device__ __forceinline__ float elu1(float x){ return x > 0.0f ? x : __expf(x) - 1.0f; }

// ---------------- CSR build (by dst) ----------------
__global__ void count_kernel(const int* __restrict__ dst, int E, int N, int* __restrict__ counts){
  int i = blockIdx.x * blockDim.x + threadIdx.x;
  if (i < E + N){
    int d = (i < E) ? dst[i] : (i - E);
    atomicAdd(&counts[d], 1);
  }
}

__global__ __launch_bounds__(256) void scan_kernel(const int* __restrict__ counts, int N, int* __restrict__ offsets){
  __shared__ int wsum[4];
  __shared__ int carry_s;
  const int lane = threadIdx.x & 63;
  const int wave = threadIdx.x >> 6;
  if (threadIdx.x == 0) carry_s = 0;
  __syncthreads();
  for (int start = 0; start < N; start += 256){
    int i = start + (int)threadIdx.x;
    int v = (i < N) ? counts[i] : 0;
    int sc = v;
    #pragma unroll
    for (int ofs = 1; ofs < 64; ofs <<= 1){
      int t = __shfl_up(sc, ofs);
      if (lane >= ofs) sc += t;
    }
    if (lane == 63) wsum[wave] = sc;
    __syncthreads();                        // (a) wsum visible
    int woff = 0;
    #pragma unroll
    for (int w = 0; w < 4; ++w) if (w < wave) woff += wsum[w];
    if (i < N) offsets[i] = carry_s + woff + sc - v;
    __syncthreads();                        // (b) carry reads done
    if (threadIdx.x == 0) carry_s += wsum[0] + wsum[1] + wsum[2] + wsum[3];
    __syncthreads();                        // (c) update visible
  }
  if (threadIdx.x == 0) offsets[N] = carry_s;
}

__global__ void fill_kernel(const int* __restrict__ src, const int* __restrict__ dst, int E, int N,
                            const int* __restrict__ offsets, int* __restrict__ cursor, int* __restrict__ csr_src){
  int i = blockIdx.x * blockDim.x + threadIdx.x;
  if (i < E + N){
    int s, d;
    if (i < E){ s = src[i]; d = dst[i]; } else { s = i - E; d = i - E; }
    int pos = atomicAdd(&cursor[d], 1);
    csr_src[offsets[d] + pos] = s;
  }
}

// ---------------- fp32 tiled GEMM: C[M,Nn] = A[M,K] @ B[K,Nn], Nn%64==0, K%32==0 ----------------
__global__ __launch_bounds__(256) void gemm_f32(const float* __restrict__ A, const float* __restrict__ B,
                                                float* __restrict__ C, int M, int Nn, int K){
  __shared__ float As[128][36];
  __shared__ float Bs[32][68];
  const int tid = threadIdx.x;
  const int tx = tid & 15;
  const int ty = tid >> 4;
  const int row0 = blockIdx.x * 128;
  const int col0 = blockIdx.y * 64;
  float acc[8][4];
  #pragma unroll
  for (int i = 0; i < 8; ++i)
    #pragma unroll
    for (int j = 0; j < 4; ++j) acc[i][j] = 0.0f;

  const int lin = tid * 4;
  const int ar = lin >> 5;      // 0..31
  const int ac = lin & 31;
  const int br = lin >> 6;      // 0..15
  const int bc = lin & 63;

  for (int k0 = 0; k0 < K; k0 += 32){
    #pragma unroll
    for (int it = 0; it < 4; ++it){
      int rr = ar + it * 32;
      int grow = row0 + rr;
      float4 v = make_float4(0.f, 0.f, 0.f, 0.f);
      if (grow < M) v = *(const float4*)(A + (size_t)grow * K + k0 + ac);
      *(float4*)&As[rr][ac] = v;
    }
    #pragma unroll
    for (int it = 0; it < 2; ++it){
      int rr = br + it * 16;
      float4 v = *(const float4*)(B + (size_t)(k0 + rr) * Nn + col0 + bc);
      *(float4*)&Bs[rr][bc] = v;
    }
    __syncthreads();
    #pragma unroll
    for (int kk = 0; kk < 32; ++kk){
      float4 b4 = *(const float4*)&Bs[kk][tx * 4];
      #pragma unroll
      for (int i = 0; i < 8; ++i){
        float av = As[ty + 16 * i][kk];
        acc[i][0] += av * b4.x;
        acc[i][1] += av * b4.y;
        acc[i][2] += av * b4.z;
        acc[i][3] += av * b4.w;
      }
    }
    __syncthreads();
  }
  #pragma unroll
  for (int i = 0; i < 8; ++i){
    int grow = row0 + ty + 16 * i;
    if (grow < M){
      float4 v = make_float4(acc[i][0], acc[i][1], acc[i][2], acc[i][3]);
      *(float4*)(C + (size_t)grow * Nn + col0 + tx * 4) = v;
    }
  }
}

// ---------------- narrow GEMM: Y[M,16] = X[M,K] @ W[K,16], K<=512, K%64==0 ----------------
__global__ __launch_bounds__(256) void gemm_n16(const float* __restrict__ X, const float* __restrict__ W,
                                                float* __restrict__ Y, int M, int K){
  __shared__ float Ws[512 * 16];
  __shared__ float Xs[64][68];
  const int tid = threadIdx.x;
  for (int i = tid; i < K * 16; i += 256) Ws[i] = W[i];
  const int tx = tid & 15;
  const int ty = tid >> 4;
  const int row0 = blockIdx.x * 64;
  float acc[4] = {0.f, 0.f, 0.f, 0.f};
  const int lin = tid * 4;
  const int xr = lin >> 6;
  const int xc = lin & 63;
  for (int k0 = 0; k0 < K; k0 += 64){
    __syncthreads();
    #pragma unroll
    for (int it = 0; it < 4; ++it){
      int rr = xr + it * 16;
      int grow = row0 + rr;
      float4 v = make_float4(0.f, 0.f, 0.f, 0.f);
      if (grow < M) v = *(const float4*)(X + (size_t)grow * K + k0 + xc);
      *(float4*)&Xs[rr][xc] = v;
    }
    __syncthreads();
    #pragma unroll
    for (int kk = 0; kk < 64; ++kk){
      float w = Ws[(k0 + kk) * 16 + tx];
      #pragma unroll
      for (int i = 0; i < 4; ++i) acc[i] += Xs[ty * 4 + i][kk] * w;
    }
  }
  #pragma unroll
  for (int i = 0; i < 4; ++i){
    int grow = row0 + ty * 4 + i;
    if (grow < M) Y[(size_t)grow * 16 + tx] = acc[i];
  }
}

// ---------------- per-node attention coefficients: AS/AD [N,8] from Hm [N,512] ----------------
__global__ __launch_bounds__(256) void alpha_kernel(
    const float* __restrict__ Hm, const float* __restrict__ a_src, const float* __restrict__ a_dst,
    float* __restrict__ AS, float* __restrict__ AD, int N)
{
  const int wave = threadIdx.x >> 6, lane = threadIdx.x & 63;
  const int n = blockIdx.x * 4 + wave;
  if (n >= N) return;
  const float4* hp = (const float4*)(Hm + (size_t)n * 512);
  const float4* sp = (const float4*)a_src;
  const float4* dp = (const float4*)a_dst;
  float4 v0 = hp[2 * lane], v1 = hp[2 * lane + 1];
  float4 s0 = sp[2 * lane], s1 = sp[2 * lane + 1];
  float4 d0 = dp[2 * lane], d1 = dp[2 * lane + 1];
  float ps = v0.x*s0.x + v0.y*s0.y + v0.z*s0.z + v0.w*s0.w
           + v1.x*s1.x + v1.y*s1.y + v1.z*s1.z + v1.w*s1.w;
  float pd = v0.x*d0.x + v0.y*d0.y + v0.z*d0.z + v0.w*d0.w
           + v1.x*d1.x + v1.y*d1.y + v1.z*d1.z + v1.w*d1.w;
  #pragma unroll
  for (int msk = 1; msk < 8; msk <<= 1){ ps += __shfl_xor(ps, msk); pd += __shfl_xor(pd, msk); }
  if ((lane & 7) == 0){
    int h = lane >> 3;
    AS[(size_t)n * 8 + h] = ps;
    AD[(size_t)n * 8 + h] = pd;
  }
}

// ---------------- GAT aggregation for 8 heads x 64ch (layers 1,2), fused bias+ELU ----------------
__global__ __launch_bounds__(256) void agg_kernel(
    const float* __restrict__ Hm,
    const float* __restrict__ AS, const float* __restrict__ AD,
    const int* __restrict__ offsets, const int* __restrict__ csr_src,
    const float* __restrict__ bias, float* __restrict__ Out, int N, int apply_elu)
{
  const int wave = threadIdx.x >> 6, lane = threadIdx.x & 63;
  const int d = blockIdx.x * 4 + wave;
  if (d >= N) return;
  const int beg = offsets[d], end = offsets[d + 1];
  const int h8 = lane & 7;
  const float adv = AD[(size_t)d * 8 + h8];
  // pass A: online (max, denom) per head; lane handles head h8, edges (lane>>3)::8
  float m = -1e30f, den = 0.f;
  for (int slot = beg + (lane >> 3); slot < end; slot += 8){
    int s = csr_src[slot];
    float e = lrelu(AS[(size_t)s * 8 + h8] + adv);
    float mn = fmaxf(m, e);
    den = den * __expf(m - mn) + __expf(e - mn);
    m = mn;
  }
  #pragma unroll
  for (int msk = 8; msk < 64; msk <<= 1){
    float mo = __shfl_xor(m, msk);
    float dn = __shfl_xor(den, msk);
    float mn = fmaxf(m, mo);
    den = den * __expf(m - mn) + dn * __expf(mo - mn);
    m = mn;
  }
  float denv = fmaxf(den, 1e-16f);
  // lane's channels: c1 = lane*4 (head lane>>4), c2 = 256+lane*4 (head 4+(lane>>4))
  const int hA = lane >> 4;
  const int hB = 4 + hA;
  const float dAi = 1.f / __shfl(denv, hA);
  const float dBi = 1.f / __shfl(denv, hB);
  float4 acc0 = make_float4(0.f, 0.f, 0.f, 0.f);
  float4 acc1 = make_float4(0.f, 0.f, 0.f, 0.f);
  for (int slot = beg; slot < end; ++slot){
    int s = csr_src[slot];
    float e = lrelu(AS[(size_t)s * 8 + h8] + adv);
    float al = __expf(e - m);                // unnormalized alpha for head h8 (valid on lanes 0..7)
    float aA = __shfl(al, hA) * dAi;
    float aB = __shfl(al, hB) * dBi;
    const float4* hp = (const float4*)(Hm + (size_t)s * 512);
    float4 v0 = hp[lane], v1 = hp[64 + lane];
    acc0.x += aA * v0.x; acc0.y += aA * v0.y; acc0.z += aA * v0.z; acc0.w += aA * v0.w;
    acc1.x += aB * v1.x; acc1.y += aB * v1.y; acc1.z += aB * v1.z; acc1.w += aB * v1.w;
  }
  const float4* bp = (const float4*)bias;
  float4 b0 = bp[lane], b1v = bp[64 + lane];
  acc0.x += b0.x;  acc0.y += b0.y;  acc0.z += b0.z;  acc0.w += b0.w;
  acc1.x += b1v.x; acc1.y += b1v.y; acc1.z += b1v.z; acc1.w += b1v.w;
  if (apply_elu){
    acc0.x = elu1(acc0.x); acc0.y = elu1(acc0.y); acc0.z = elu1(acc0.z); acc0.w = elu1(acc0.w);
    acc1.x = elu1(acc1.x); acc1.y = elu1(acc1.y); acc1.z = elu1(acc1.z); acc1.w = elu1(acc1.w);
  }
  float4* op = (float4*)(Out + (size_t)d * 512);
  op[lane] = acc0;
  op[64 + lane] = acc1;
}

// ---------------- layer-3 node coefficients (1 head, 16 ch) ----------------
__global__ __launch_bounds__(256) void alpha3_kernel(const float* __restrict__ H3,
    const float* __restrict__ a3s, const float* __restrict__ a3d,
    float* __restrict__ AS3, float* __restrict__ AD3, int N){
  const int lane = threadIdx.x & 63;
  const int wave = threadIdx.x >> 6;
  const int c = lane & 15;
  const int n = blockIdx.x * 16 + wave * 4 + (lane >> 4);
  float v = (n < N) ? H3[(size_t)n * 16 + c] : 0.f;
  float ps = v * a3s[c];
  float pd = v * a3d[c];
  #pragma unroll
  for (int msk = 1; msk < 16; msk <<= 1){ ps += __shfl_xor(ps, msk); pd += __shfl_xor(pd, msk); }
  if (c == 0 && n < N){ AS3[n] = ps; AD3[n] = pd; }
}

// ---------------- layer-3 aggregation (1 head, 16 ch) + bias + log_softmax ----------------
__global__ __launch_bounds__(256) void agg3_kernel(
    const float* __restrict__ H3,
    const float* __restrict__ AS3, const float* __restrict__ AD3,
    const int* __restrict__ offsets, const int* __restrict__ csr_src,
    const float* __restrict__ bias, float* __restrict__ Out, int N)
{
  const int wave = threadIdx.x >> 6, lane = threadIdx.x & 63;
  const int d = blockIdx.x * 4 + wave;
  if (d >= N) return;
  const int beg = offsets[d], end = offsets[d + 1];
  const float adv = AD3[d];
  float m = -1e30f, den = 0.f;
  for (int slot = beg + lane; slot < end; slot += 64){
    int s = csr_src[slot];
    float e = lrelu(AS3[s] + adv);
    float mn = fmaxf(m, e);
    den = den * __expf(m - mn) + __expf(e - mn);
    m = mn;
  }
  #pragma unroll
  for (int msk = 1; msk < 64; msk <<= 1){
    float mo = __shfl_xor(m, msk);
    float dn = __shfl_xor(den, msk);
    float mn = fmaxf(m, mo);
    den = den * __expf(m - mn) + dn * __expf(mo - mn);
    m = mn;
  }
  float denv = fmaxf(den, 1e-16f);
  const int c = lane & 15;
  float acc = 0.f;
  for (int slot = beg + (lane >> 4); slot < end; slot += 4){
    int s = csr_src[slot];
    float al = __expf(lrelu(AS3[s] + adv) - m) / denv;
    acc += al * H3[(size_t)s * 16 + c];
  }
  acc += __shfl_xor(acc, 16);
  acc += __shfl_xor(acc, 32);
  float v = acc + bias[c];
  float mm = v;
  #pragma unroll
  for (int msk = 1; msk < 16; msk <<= 1) mm = fmaxf(mm, __shfl_xor(mm, msk));
  float se = __expf(v - mm);
  #pragma unroll
  for (int msk = 1; msk < 16; msk <<= 1) se += __shfl_xor(se, msk);
  float r = v - mm - __logf(se);
  if (lane < 16) Out[(size_t)d * 16 + lane] = r;
}

extern "C" void kernel_launch(void* const* d_in, const int* in_sizes, int n_in,
                              void* d_out, int out_size, void* d_ws, size_t ws_size,
                              hipStream_t stream)
{
  const float* x   = (const float*)d_in[0];
  const int*   ei  = (const int*)d_in[1];
  const float* W1  = (const float*)d_in[2];
  const float* as1 = (const float*)d_in[3];
  const float* ad1 = (const float*)d_in[4];
  const float* b1  = (const float*)d_in[5];
  const float* W2  = (const float*)d_in[6];
  const float* as2 = (const float*)d_in[7];
  const float* ad2 = (const float*)d_in[8];
  const float* b2  = (const float*)d_in[9];
  const float* W3  = (const float*)d_in[10];
  const float* as3 = (const float*)d_in[11];
  const float* ad3 = (const float*)d_in[12];
  const float* b3  = (const float*)d_in[13];

  const int N  = in_sizes[0] / 256;
  const int E  = in_sizes[1] / 2;
  const int Et = E + N;
  const int* src = ei;
  const int* dst = ei + E;

  char* base = (char*)d_ws;
  size_t off = 0;
  auto take = [&](size_t bytes) -> char* {
    char* p = base + off;
    off = (off + bytes + 255) & ~(size_t)255;
    return p;
  };
  float* Hbuf = (float*)take((size_t)N * 512 * 4);
  float* Obuf = (float*)take((size_t)N * 512 * 4);
  float* AS   = (float*)take((size_t)N * 8 * 4);
  float* AD   = (float*)take((size_t)N * 8 * 4);
  float* H3   = (float*)take((size_t)N * 16 * 4);
  float* AS3  = (float*)take((size_t)N * 4);
  float* AD3  = (float*)take((size_t)N * 4);
  int* counts  = (int*)take((size_t)2 * N * 4);   // counts + cursor adjacent
  int* cursor  = counts + N;
  int* offsets = (int*)take((size_t)(N + 1) * 4);
  int* csr     = (int*)take((size_t)Et * 4);
  if (off > ws_size) return;   // workspace too small; bail

  hipMemsetAsync(counts, 0, (size_t)2 * N * 4, stream);
  const int tb = 256;
  count_kernel<<<(Et + tb - 1) / tb, tb, 0, stream>>>(dst, E, N, counts);
  scan_kernel<<<1, 256, 0, stream>>>(counts, N, offsets);
  fill_kernel<<<(Et + tb - 1) / tb, tb, 0, stream>>>(src, dst, E, N, offsets, cursor, csr);

  dim3 g1((N + 127) / 128, 8);
  // layer 1
  gemm_f32<<<g1, 256, 0, stream>>>(x, W1, Hbuf, N, 512, 256);
  alpha_kernel<<<(N + 3) / 4, 256, 0, stream>>>(Hbuf, as1, ad1, AS, AD, N);
  agg_kernel<<<(N + 3) / 4, 256, 0, stream>>>(Hbuf, AS, AD, offsets, csr, b1, Obuf, N, 1);
  // layer 2
  gemm_f32<<<g1, 256, 0, stream>>>(Obuf, W2, Hbuf, N, 512, 512);
  alpha_kernel<<<(N + 3) / 4, 256, 0, stream>>>(Hbuf, as2, ad2, AS, AD, N);
  agg_kernel<<<(N + 3) / 4, 256, 0, stream>>>(Hbuf, AS, AD, offsets, csr, b2, Obuf, N, 1);
  // layer 3
  gemm_n16<<<(N + 63) / 64, 256, 0, stream>>>(Obuf, W3, H3, N, 512);
  alpha3_kernel<<<(N + 15) / 16, 256, 0, stream>>>(H3, as3, ad3, AS3, AD3, N);
  agg3_kernel<<<(N + 3) / 4, 256, 0, stream>>>(H3, AS3, AD3, offsets, csr, b3, (float*)d_out, N);
}

// Round 2
// 334.949 us; speedup vs baseline: 1.7068x; 1.7068x over previous
//
#include <hip/hip_runtime.h>

#define NEG_SLOPE 0.2f

typedef _Float16 f16x8 __attribute__((ext_vector_type(8)));
typedef float f32x4 __attribute__((ext_vector_type(4)));

__device__ __forceinline__ float lrelu(float x){ return x >= 0.0f ? x : NEG_SLOPE * x; }
__device__ __forceinline__ float elu1(float x){ return x > 0.0f ? x : __expf(x) - 1.0f; }

__device__ __forceinline__ void gload_lds16(const _Float16* g, _Float16* l){
  __builtin_amdgcn_global_load_lds(
      (const __attribute__((address_space(1))) unsigned int*)g,
      (__attribute__((address_space(3))) unsigned int*)l, 16, 0, 0);
}

union H8U { uint4 u; _Float16 h[8]; };

// ---------------- CSR build (by dst) ----------------
__global__ void count_kernel(const int* __restrict__ dst, int E, int N, int* __restrict__ counts){
  int i = blockIdx.x * blockDim.x + threadIdx.x;
  if (i < E + N){
    int d = (i < E) ? dst[i] : (i - E);
    atomicAdd(&counts[d], 1);
  }
}

__global__ __launch_bounds__(256) void scan_kernel(const int* __restrict__ counts, int N, int* __restrict__ offsets){
  __shared__ int wsum[4];
  __shared__ int carry_s;
  const int lane = threadIdx.x & 63;
  const int wave = threadIdx.x >> 6;
  if (threadIdx.x == 0) carry_s = 0;
  __syncthreads();
  for (int start = 0; start < N; start += 256){
    int i = start + (int)threadIdx.x;
    int v = (i < N) ? counts[i] : 0;
    int sc = v;
    #pragma unroll
    for (int ofs = 1; ofs < 64; ofs <<= 1){
      int t = __shfl_up(sc, ofs);
      if (lane >= ofs) sc += t;
    }
    if (lane == 63) wsum[wave] = sc;
    __syncthreads();
    int woff = 0;
    #pragma unroll
    for (int w = 0; w < 4; ++w) if (w < wave) woff += wsum[w];
    if (i < N) offsets[i] = carry_s + woff + sc - v;
    __syncthreads();
    if (threadIdx.x == 0) carry_s += wsum[0] + wsum[1] + wsum[2] + wsum[3];
    __syncthreads();
  }
  if (threadIdx.x == 0) offsets[N] = carry_s;
}

__global__ void fill_kernel(const int* __restrict__ src, const int* __restrict__ dst, int E, int N,
                            const int* __restrict__ offsets, int* __restrict__ cursor, int* __restrict__ csr_src){
  int i = blockIdx.x * blockDim.x + threadIdx.x;
  if (i < E + N){
    int s, d;
    if (i < E){ s = src[i]; d = dst[i]; } else { s = i - E; d = i - E; }
    int pos = atomicAdd(&cursor[d], 1);
    csr_src[offsets[d] + pos] = s;
  }
}

// ---------------- conversions ----------------
__global__ void convert_x_f16(const float* __restrict__ X, _Float16* __restrict__ X16, int valid, int total){
  int i = (blockIdx.x * blockDim.x + threadIdx.x) * 8;
  if (i >= total) return;
  H8U o;
  if (i + 8 <= valid){
    float4 v0 = *(const float4*)(X + i);
    float4 v1 = *(const float4*)(X + i + 4);
    o.h[0] = (_Float16)v0.x; o.h[1] = (_Float16)v0.y; o.h[2] = (_Float16)v0.z; o.h[3] = (_Float16)v0.w;
    o.h[4] = (_Float16)v1.x; o.h[5] = (_Float16)v1.y; o.h[6] = (_Float16)v1.z; o.h[7] = (_Float16)v1.w;
  } else {
    #pragma unroll
    for (int j = 0; j < 8; ++j) o.h[j] = (i + j < valid) ? (_Float16)X[i + j] : (_Float16)0.0f;
  }
  *(uint4*)(X16 + i) = o.u;
}

// W [K,Nn] fp32 -> WT [Nn,K] fp16 ; K,Nn multiples of 32
__global__ __launch_bounds__(256) void transpose_w_f16(const float* __restrict__ W, _Float16* __restrict__ WT, int K, int Nn){
  __shared__ float tile[32][33];
  const int k0 = blockIdx.x * 32, n0 = blockIdx.y * 32;
  const int tx = threadIdx.x & 31, ty = threadIdx.x >> 5;  // ty 0..7
  for (int i = ty; i < 32; i += 8)
    tile[i][tx] = W[(size_t)(k0 + i) * Nn + n0 + tx];
  __syncthreads();
  for (int i = ty; i < 32; i += 8)
    WT[(size_t)(n0 + i) * K + k0 + tx] = (_Float16)tile[tx][i];
}

// ---------------- fp16 MFMA GEMM: C[M,Nn](f16) = A[Mpad,K](f16) @ BT[Nn,K](f16)^T ----------------
// 128x128 tile, 4 waves (2x2), BK=64, 16x16x32 MFMA
__global__ __launch_bounds__(256) void gemm_f16_mfma(
    const _Float16* __restrict__ A, const _Float16* __restrict__ BT,
    _Float16* __restrict__ C, int M, int Nn, int K)
{
  __shared__ _Float16 As[128 * 64];
  __shared__ _Float16 Bs[128 * 64];
  const int tid = threadIdx.x;
  const int lane = tid & 63;
  const int wave = tid >> 6;
  const int wr = wave >> 1, wc = wave & 1;
  const int row0 = blockIdx.x * 128;
  const int col0 = blockIdx.y * 128;
  const int r15 = lane & 15;
  const int kgrp = lane >> 4;   // 0..3

  f32x4 acc[4][4];
  #pragma unroll
  for (int m = 0; m < 4; ++m)
    #pragma unroll
    for (int n = 0; n < 4; ++n)
      acc[m][n] = (f32x4){0.f, 0.f, 0.f, 0.f};

  for (int k0 = 0; k0 < K; k0 += 64){
    #pragma unroll
    for (int it = 0; it < 4; ++it){
      int idx = it * 2048 + tid * 8;
      int r = idx >> 6, c = idx & 63;
      gload_lds16(A  + (size_t)(row0 + r) * K + k0 + c, &As[idx]);
      gload_lds16(BT + (size_t)(col0 + r) * K + k0 + c, &Bs[idx]);
    }
    __syncthreads();
    #pragma unroll
    for (int kk = 0; kk < 2; ++kk){
      const int cc = kk * 32 + kgrp * 8;
      f16x8 a0 = *(const f16x8*)&As[(wr * 64 +  0 + r15) * 64 + cc];
      f16x8 a1 = *(const f16x8*)&As[(wr * 64 + 16 + r15) * 64 + cc];
      f16x8 a2 = *(const f16x8*)&As[(wr * 64 + 32 + r15) * 64 + cc];
      f16x8 a3 = *(const f16x8*)&As[(wr * 64 + 48 + r15) * 64 + cc];
      f16x8 b0 = *(const f16x8*)&Bs[(wc * 64 +  0 + r15) * 64 + cc];
      f16x8 b1 = *(const f16x8*)&Bs[(wc * 64 + 16 + r15) * 64 + cc];
      f16x8 b2 = *(const f16x8*)&Bs[(wc * 64 + 32 + r15) * 64 + cc];
      f16x8 b3 = *(const f16x8*)&Bs[(wc * 64 + 48 + r15) * 64 + cc];
      f16x8 av[4] = {a0, a1, a2, a3};
      f16x8 bv[4] = {b0, b1, b2, b3};
      #pragma unroll
      for (int m = 0; m < 4; ++m)
        #pragma unroll
        for (int n = 0; n < 4; ++n)
          acc[m][n] = __builtin_amdgcn_mfma_f32_16x16x32_f16(av[m], bv[n], acc[m][n], 0, 0, 0);
    }
    __syncthreads();
  }
  #pragma unroll
  for (int m = 0; m < 4; ++m){
    #pragma unroll
    for (int n = 0; n < 4; ++n){
      int col = col0 + wc * 64 + n * 16 + r15;
      #pragma unroll
      for (int j = 0; j < 4; ++j){
        int row = row0 + wr * 64 + m * 16 + kgrp * 4 + j;
        if (row < M) C[(size_t)row * Nn + col] = (_Float16)acc[m][n][j];
      }
    }
  }
}

// ---------------- per-node attention coefficients from fp16 H ----------------
__global__ __launch_bounds__(256) void alpha_f16(
    const _Float16* __restrict__ H16, const float* __restrict__ a_src, const float* __restrict__ a_dst,
    float* __restrict__ AS, float* __restrict__ AD, int N)
{
  const int wave = threadIdx.x >> 6, lane = threadIdx.x & 63;
  const int n = blockIdx.x * 4 + wave;
  if (n >= N) return;
  H8U U; U.u = *(const uint4*)(H16 + (size_t)n * 512 + lane * 8);
  const int head = lane >> 3, ch8 = lane & 7;
  const float4* sp = (const float4*)(a_src + head * 64 + ch8 * 8);
  const float4* dp = (const float4*)(a_dst + head * 64 + ch8 * 8);
  float4 s0 = sp[0], s1 = sp[1], d0 = dp[0], d1 = dp[1];
  float v[8];
  #pragma unroll
  for (int j = 0; j < 8; ++j) v[j] = (float)U.h[j];
  float ps = v[0]*s0.x + v[1]*s0.y + v[2]*s0.z + v[3]*s0.w
           + v[4]*s1.x + v[5]*s1.y + v[6]*s1.z + v[7]*s1.w;
  float pd = v[0]*d0.x + v[1]*d0.y + v[2]*d0.z + v[3]*d0.w
           + v[4]*d1.x + v[5]*d1.y + v[6]*d1.z + v[7]*d1.w;
  #pragma unroll
  for (int msk = 1; msk < 8; msk <<= 1){ ps += __shfl_xor(ps, msk); pd += __shfl_xor(pd, msk); }
  if (ch8 == 0){
    AS[(size_t)n * 8 + head] = ps;
    AD[(size_t)n * 8 + head] = pd;
  }
}

// ---------------- GAT aggregation, fp16 gather, fused bias+ELU, fp16 out ----------------
__global__ __launch_bounds__(256) void agg_f16(
    const _Float16* __restrict__ H16,
    const float* __restrict__ AS, const float* __restrict__ AD,
    const int* __restrict__ offsets, const int* __restrict__ csr_src,
    const float* __restrict__ bias, _Float16* __restrict__ O16, int N)
{
  const int wave = threadIdx.x >> 6, lane = threadIdx.x & 63;
  const int d = blockIdx.x * 4 + wave;
  if (d >= N) return;
  const int beg = offsets[d], end = offsets[d + 1];
  const int h8 = lane & 7;
  const float adv = AD[(size_t)d * 8 + h8];
  // pass A: online (max, denom) for head h8; edge groups strided by lane>>3
  float m = -1e30f, den = 0.f;
  for (int slot = beg + (lane >> 3); slot < end; slot += 8){
    int s = csr_src[slot];
    float e = lrelu(AS[(size_t)s * 8 + h8] + adv);
    float mn = fmaxf(m, e);
    den = den * __expf(m - mn) + __expf(e - mn);
    m = mn;
  }
  #pragma unroll
  for (int msk = 8; msk < 64; msk <<= 1){
    float mo = __shfl_xor(m, msk);
    float dn = __shfl_xor(den, msk);
    float mn = fmaxf(m, mo);
    den = den * __expf(m - mn) + dn * __expf(mo - mn);
    m = mn;
  }
  // lane owns channels lane*8..lane*8+7, i.e. head hA = lane>>3
  const int hA = lane >> 3;
  const float dAi = 1.f / fmaxf(__shfl(den, hA), 1e-16f);
  float acc[8];
  #pragma unroll
  for (int j = 0; j < 8; ++j) acc[j] = 0.f;
  for (int slot = beg; slot < end; ++slot){
    int s = csr_src[slot];
    float e = lrelu(AS[(size_t)s * 8 + h8] + adv);
    float al = __expf(e - m);              // unnormalized alpha for head h8 (lanes 0..7 are sources)
    float a = __shfl(al, hA) * dAi;
    H8U U; U.u = *(const uint4*)(H16 + (size_t)s * 512 + lane * 8);
    #pragma unroll
    for (int j = 0; j < 8; ++j) acc[j] += a * (float)U.h[j];
  }
  const float4 b0 = *(const float4*)(bias + lane * 8);
  const float4 b1 = *(const float4*)(bias + lane * 8 + 4);
  acc[0] += b0.x; acc[1] += b0.y; acc[2] += b0.z; acc[3] += b0.w;
  acc[4] += b1.x; acc[5] += b1.y; acc[6] += b1.z; acc[7] += b1.w;
  H8U O;
  #pragma unroll
  for (int j = 0; j < 8; ++j) O.h[j] = (_Float16)elu1(acc[j]);
  *(uint4*)(O16 + (size_t)d * 512 + lane * 8) = O.u;
}

// ---------------- narrow GEMM: Y[M,16](f32) = X[Mpad,512](f16) @ W[512,16](f32) ----------------
__global__ __launch_bounds__(256) void gemm_n16_f16(const _Float16* __restrict__ X, const float* __restrict__ W,
                                                    float* __restrict__ Y, int M, int K){
  __shared__ float Ws[512 * 16];
  __shared__ float Xs[64][68];
  const int tid = threadIdx.x;
  for (int i = tid; i < K * 16; i += 256) Ws[i] = W[i];
  const int tx = tid & 15;
  const int ty = tid >> 4;
  const int row0 = blockIdx.x * 64;
  float acc[4] = {0.f, 0.f, 0.f, 0.f};
  for (int k0 = 0; k0 < K; k0 += 64){
    __syncthreads();
    #pragma unroll
    for (int it = 0; it < 2; ++it){
      int idx = it * 2048 + tid * 8;
      int r = idx >> 6, c = idx & 63;
      H8U U; U.u = *(const uint4*)(X + (size_t)(row0 + r) * K + k0 + c);
      float4 f0 = make_float4((float)U.h[0], (float)U.h[1], (float)U.h[2], (float)U.h[3]);
      float4 f1 = make_float4((float)U.h[4], (float)U.h[5], (float)U.h[6], (float)U.h[7]);
      *(float4*)&Xs[r][c] = f0;
      *(float4*)&Xs[r][c + 4] = f1;
    }
    __syncthreads();
    #pragma unroll
    for (int kk = 0; kk < 64; ++kk){
      float w = Ws[(k0 + kk) * 16 + tx];
      #pragma unroll
      for (int i = 0; i < 4; ++i) acc[i] += Xs[ty * 4 + i][kk] * w;
    }
  }
  #pragma unroll
  for (int i = 0; i < 4; ++i){
    int grow = row0 + ty * 4 + i;
    if (grow < M) Y[(size_t)grow * 16 + tx] = acc[i];
  }
}

// ---------------- layer-3 node coefficients (1 head, 16 ch) ----------------
__global__ __launch_bounds__(256) void alpha3_kernel(const float* __restrict__ H3,
    const float* __restrict__ a3s, const float* __restrict__ a3d,
    float* __restrict__ AS3, float* __restrict__ AD3, int N){
  const int lane = threadIdx.x & 63;
  const int wave = threadIdx.x >> 6;
  const int c = lane & 15;
  const int n = blockIdx.x * 16 + wave * 4 + (lane >> 4);
  float v = (n < N) ? H3[(size_t)n * 16 + c] : 0.f;
  float ps = v * a3s[c];
  float pd = v * a3d[c];
  #pragma unroll
  for (int msk = 1; msk < 16; msk <<= 1){ ps += __shfl_xor(ps, msk); pd += __shfl_xor(pd, msk); }
  if (c == 0 && n < N){ AS3[n] = ps; AD3[n] = pd; }
}

// ---------------- layer-3 aggregation (1 head, 16 ch) + bias + log_softmax ----------------
__global__ __launch_bounds__(256) void agg3_kernel(
    const float* __restrict__ H3,
    const float* __restrict__ AS3, const float* __restrict__ AD3,
    const int* __restrict__ offsets, const int* __restrict__ csr_src,
    const float* __restrict__ bias, float* __restrict__ Out, int N)
{
  const int wave = threadIdx.x >> 6, lane = threadIdx.x & 63;
  const int d = blockIdx.x * 4 + wave;
  if (d >= N) return;
  const int beg = offsets[d], end = offsets[d + 1];
  const float adv = AD3[d];
  float m = -1e30f, den = 0.f;
  for (int slot = beg + lane; slot < end; slot += 64){
    int s = csr_src[slot];
    float e = lrelu(AS3[s] + adv);
    float mn = fmaxf(m, e);
    den = den * __expf(m - mn) + __expf(e - mn);
    m = mn;
  }
  #pragma unroll
  for (int msk = 1; msk < 64; msk <<= 1){
    float mo = __shfl_xor(m, msk);
    float dn = __shfl_xor(den, msk);
    float mn = fmaxf(m, mo);
    den = den * __expf(m - mn) + dn * __expf(mo - mn);
    m = mn;
  }
  float denv = fmaxf(den, 1e-16f);
  const int c = lane & 15;
  float acc = 0.f;
  for (int slot = beg + (lane >> 4); slot < end; slot += 4){
    int s = csr_src[slot];
    float al = __expf(lrelu(AS3[s] + adv) - m) / denv;
    acc += al * H3[(size_t)s * 16 + c];
  }
  acc += __shfl_xor(acc, 16);
  acc += __shfl_xor(acc, 32);
  float v = acc + bias[c];
  float mm = v;
  #pragma unroll
  for (int msk = 1; msk < 16; msk <<= 1) mm = fmaxf(mm, __shfl_xor(mm, msk));
  float se = __expf(v - mm);
  #pragma unroll
  for (int msk = 1; msk < 16; msk <<= 1) se += __shfl_xor(se, msk);
  float r = v - mm - __logf(se);
  if (lane < 16) Out[(size_t)d * 16 + lane] = r;
}

extern "C" void kernel_launch(void* const* d_in, const int* in_sizes, int n_in,
                              void* d_out, int out_size, void* d_ws, size_t ws_size,
                              hipStream_t stream)
{
  const float* x   = (const float*)d_in[0];
  const int*   ei  = (const int*)d_in[1];
  const float* W1  = (const float*)d_in[2];
  const float* as1 = (const float*)d_in[3];
  const float* ad1 = (const float*)d_in[4];
  const float* b1  = (const float*)d_in[5];
  const float* W2  = (const float*)d_in[6];
  const float* as2 = (const float*)d_in[7];
  const float* ad2 = (const float*)d_in[8];
  const float* b2  = (const float*)d_in[9];
  const float* W3  = (const float*)d_in[10];
  const float* as3 = (const float*)d_in[11];
  const float* ad3 = (const float*)d_in[12];
  const float* b3  = (const float*)d_in[13];

  const int N    = in_sizes[0] / 256;
  const int E    = in_sizes[1] / 2;
  const int Et   = E + N;
  const int Mpad = (N + 127) & ~127;   // 20096
  const int* src = ei;
  const int* dst = ei + E;

  char* base = (char*)d_ws;
  size_t off = 0;
  auto take = [&](size_t bytes) -> char* {
    char* p = base + off;
    off = (off + bytes + 255) & ~(size_t)255;
    return p;
  };
  _Float16* x16  = (_Float16*)take((size_t)Mpad * 256 * 2);
  _Float16* H16  = (_Float16*)take((size_t)Mpad * 512 * 2);
  _Float16* O16  = (_Float16*)take((size_t)Mpad * 512 * 2);
  _Float16* W1T  = (_Float16*)take((size_t)512 * 256 * 2);
  _Float16* W2T  = (_Float16*)take((size_t)512 * 512 * 2);
  float* AS   = (float*)take((size_t)N * 8 * 4);
  float* AD   = (float*)take((size_t)N * 8 * 4);
  float* H3   = (float*)take((size_t)N * 16 * 4);
  float* AS3  = (float*)take((size_t)N * 4);
  float* AD3  = (float*)take((size_t)N * 4);
  int* counts  = (int*)take((size_t)2 * N * 4);
  int* cursor  = counts + N;
  int* offsets = (int*)take((size_t)(N + 1) * 4);
  int* csr     = (int*)take((size_t)Et * 4);
  if (off > ws_size) return;

  hipMemsetAsync(counts, 0, (size_t)2 * N * 4, stream);
  const int tb = 256;
  count_kernel<<<(Et + tb - 1) / tb, tb, 0, stream>>>(dst, E, N, counts);
  scan_kernel<<<1, 256, 0, stream>>>(counts, N, offsets);
  fill_kernel<<<(Et + tb - 1) / tb, tb, 0, stream>>>(src, dst, E, N, offsets, cursor, csr);

  // input conversions
  {
    int total = Mpad * 256, valid = N * 256;
    convert_x_f16<<<(total / 8 + tb - 1) / tb, tb, 0, stream>>>(x, x16, valid, total);
  }
  transpose_w_f16<<<dim3(256 / 32, 512 / 32), 256, 0, stream>>>(W1, W1T, 256, 512);
  transpose_w_f16<<<dim3(512 / 32, 512 / 32), 256, 0, stream>>>(W2, W2T, 512, 512);

  const int gM = Mpad / 128;
  // layer 1
  gemm_f16_mfma<<<dim3(gM, 4), 256, 0, stream>>>(x16, W1T, H16, N, 512, 256);
  alpha_f16<<<(N + 3) / 4, 256, 0, stream>>>(H16, as1, ad1, AS, AD, N);
  agg_f16<<<(N + 3) / 4, 256, 0, stream>>>(H16, AS, AD, offsets, csr, b1, O16, N);
  // layer 2
  gemm_f16_mfma<<<dim3(gM, 4), 256, 0, stream>>>(O16, W2T, H16, N, 512, 512);
  alpha_f16<<<(N + 3) / 4, 256, 0, stream>>>(H16, as2, ad2, AS, AD, N);
  agg_f16<<<(N + 3) / 4, 256, 0, stream>>>(H16, AS, AD, offsets, csr, b2, O16, N);
  // layer 3
  gemm_n16_f16<<<(N + 63) / 64, 256, 0, stream>>>(O16, W3, H3, N, 512);
  alpha3_kernel<<<(N + 15) / 16, 256, 0, stream>>>(H3, as3, ad3, AS3, AD3, N);
  agg3_kernel<<<(N + 3) / 4, 256, 0, stream>>>(H3, AS3, AD3, offsets, csr, b3, (float*)d_out, N);
}

// Round 3
// 269.869 us; speedup vs baseline: 2.1184x; 1.2412x over previous
//
#include <hip/hip_runtime.h>

#define NEG_SLOPE 0.2f

typedef _Float16 f16x8 __attribute__((ext_vector_type(8)));
typedef float f32x4 __attribute__((ext_vector_type(4)));

__device__ __forceinline__ float lrelu(float x){ return x >= 0.0f ? x : NEG_SLOPE * x; }
__device__ __forceinline__ float elu1(float x){ return x > 0.0f ? x : __expf(x) - 1.0f; }

__device__ __forceinline__ void gload_lds16(const _Float16* g, _Float16* l){
  __builtin_amdgcn_global_load_lds(
      (const __attribute__((address_space(1))) unsigned int*)g,
      (__attribute__((address_space(3))) unsigned int*)l, 16, 0, 0);
}

union H8U { uint4 u; _Float16 h[8]; };

// ---------------- CSR build (by dst) ----------------
__global__ void count_kernel(const int* __restrict__ dst, int E, int N, int* __restrict__ counts){
  int i = blockIdx.x * blockDim.x + threadIdx.x;
  if (i < E + N){
    int d = (i < E) ? dst[i] : (i - E);
    atomicAdd(&counts[d], 1);
  }
}

__global__ __launch_bounds__(256) void block_sum_kernel(const int* __restrict__ counts, int N, int* __restrict__ bsum){
  __shared__ int ws[4];
  const int lane = threadIdx.x & 63, wave = threadIdx.x >> 6;
  int i = blockIdx.x * 256 + threadIdx.x;
  int v = (i < N) ? counts[i] : 0;
  #pragma unroll
  for (int msk = 1; msk < 64; msk <<= 1) v += __shfl_xor(v, msk);
  if (lane == 0) ws[wave] = v;
  __syncthreads();
  if (threadIdx.x == 0) bsum[blockIdx.x] = ws[0] + ws[1] + ws[2] + ws[3];
}

__global__ __launch_bounds__(256) void scan_bsum_kernel(int* __restrict__ bsum, int nb, int* __restrict__ offsets, int N){
  __shared__ int tmp[256];
  const int t = threadIdx.x;
  int v = (t < nb) ? bsum[t] : 0;
  tmp[t] = v;
  __syncthreads();
  #pragma unroll
  for (int ofs = 1; ofs < 256; ofs <<= 1){
    int add = (t >= ofs) ? tmp[t - ofs] : 0;
    __syncthreads();
    tmp[t] += add;
    __syncthreads();
  }
  if (t < nb) bsum[t] = tmp[t] - v;          // exclusive
  if (t == nb - 1) offsets[N] = tmp[t];      // total
}

__global__ __launch_bounds__(256) void scan_within_kernel(const int* __restrict__ counts, const int* __restrict__ bsum,
                                                          int* __restrict__ offsets, int N){
  __shared__ int wsum[4];
  const int lane = threadIdx.x & 63, wave = threadIdx.x >> 6;
  int i = blockIdx.x * 256 + threadIdx.x;
  int v = (i < N) ? counts[i] : 0;
  int sc = v;
  #pragma unroll
  for (int ofs = 1; ofs < 64; ofs <<= 1){
    int t = __shfl_up(sc, ofs);
    if (lane >= ofs) sc += t;
  }
  if (lane == 63) wsum[wave] = sc;
  __syncthreads();
  int woff = 0;
  #pragma unroll
  for (int w = 0; w < 4; ++w) if (w < wave) woff += wsum[w];
  if (i < N) offsets[i] = bsum[blockIdx.x] + woff + sc - v;
}

__global__ void fill_kernel(const int* __restrict__ src, const int* __restrict__ dst, int E, int N,
                            const int* __restrict__ offsets, int* __restrict__ cursor, int* __restrict__ csr_src){
  int i = blockIdx.x * blockDim.x + threadIdx.x;
  if (i < E + N){
    int s, d;
    if (i < E){ s = src[i]; d = dst[i]; } else { s = i - E; d = i - E; }
    int pos = atomicAdd(&cursor[d], 1);
    csr_src[offsets[d] + pos] = s;
  }
}

// ---------------- conversions ----------------
__global__ void convert_x_f16(const float* __restrict__ X, _Float16* __restrict__ X16, int valid, int total){
  int i = (blockIdx.x * blockDim.x + threadIdx.x) * 8;
  if (i >= total) return;
  H8U o;
  if (i + 8 <= valid){
    float4 v0 = *(const float4*)(X + i);
    float4 v1 = *(const float4*)(X + i + 4);
    o.h[0] = (_Float16)v0.x; o.h[1] = (_Float16)v0.y; o.h[2] = (_Float16)v0.z; o.h[3] = (_Float16)v0.w;
    o.h[4] = (_Float16)v1.x; o.h[5] = (_Float16)v1.y; o.h[6] = (_Float16)v1.z; o.h[7] = (_Float16)v1.w;
  } else {
    #pragma unroll
    for (int j = 0; j < 8; ++j) o.h[j] = (i + j < valid) ? (_Float16)X[i + j] : (_Float16)0.0f;
  }
  *(uint4*)(X16 + i) = o.u;
}

// W [K,Nn] fp32 -> WT [Nn,K] fp16
__global__ __launch_bounds__(256) void transpose_w_f16(const float* __restrict__ W, _Float16* __restrict__ WT, int K, int Nn){
  __shared__ float tile[32][33];
  const int k0 = blockIdx.x * 32, n0 = blockIdx.y * 32;
  const int tx = threadIdx.x & 31, ty = threadIdx.x >> 5;
  for (int i = ty; i < 32; i += 8)
    tile[i][tx] = W[(size_t)(k0 + i) * Nn + n0 + tx];
  __syncthreads();
  for (int i = ty; i < 32; i += 8)
    WT[(size_t)(n0 + i) * K + k0 + tx] = (_Float16)tile[tx][i];
}

// ---------------- fp16 MFMA GEMM + fused alpha epilogue ----------------
// C[M,Nn](f16) = A[Mpad,K](f16) @ BT[Nn,K]^T ; Nn=512, 128x128 tile, 4 waves
// epilogue: AS[row,head], AD[row,head] with head = 2*blockIdx.y + wc
__global__ __launch_bounds__(256) void gemm_f16_mfma(
    const _Float16* __restrict__ A, const _Float16* __restrict__ BT,
    _Float16* __restrict__ C,
    const float* __restrict__ a_src, const float* __restrict__ a_dst,
    float* __restrict__ AS, float* __restrict__ AD,
    int M, int Nn, int K)
{
  __shared__ _Float16 As[128 * 64];
  __shared__ _Float16 Bs[128 * 64];
  const int tid = threadIdx.x;
  const int lane = tid & 63;
  const int wave = tid >> 6;
  const int wr = wave >> 1, wc = wave & 1;
  const int row0 = blockIdx.x * 128;
  const int col0 = blockIdx.y * 128;
  const int r15 = lane & 15;
  const int kgrp = lane >> 4;

  f32x4 acc[4][4];
  #pragma unroll
  for (int m = 0; m < 4; ++m)
    #pragma unroll
    for (int n = 0; n < 4; ++n)
      acc[m][n] = (f32x4){0.f, 0.f, 0.f, 0.f};

  for (int k0 = 0; k0 < K; k0 += 64){
    #pragma unroll
    for (int it = 0; it < 4; ++it){
      int idx = it * 2048 + tid * 8;
      int r = idx >> 6, c = idx & 63;
      gload_lds16(A  + (size_t)(row0 + r) * K + k0 + c, &As[idx]);
      gload_lds16(BT + (size_t)(col0 + r) * K + k0 + c, &Bs[idx]);
    }
    __syncthreads();
    #pragma unroll
    for (int kk = 0; kk < 2; ++kk){
      const int cc = kk * 32 + kgrp * 8;
      f16x8 av[4], bv[4];
      #pragma unroll
      for (int q = 0; q < 4; ++q){
        av[q] = *(const f16x8*)&As[(wr * 64 + q * 16 + r15) * 64 + cc];
        bv[q] = *(const f16x8*)&Bs[(wc * 64 + q * 16 + r15) * 64 + cc];
      }
      #pragma unroll
      for (int m = 0; m < 4; ++m)
        #pragma unroll
        for (int n = 0; n < 4; ++n)
          acc[m][n] = __builtin_amdgcn_mfma_f32_16x16x32_f16(av[m], bv[n], acc[m][n], 0, 0, 0);
    }
    __syncthreads();
  }
  // C store (fp16)
  #pragma unroll
  for (int m = 0; m < 4; ++m){
    #pragma unroll
    for (int n = 0; n < 4; ++n){
      int col = col0 + wc * 64 + n * 16 + r15;
      #pragma unroll
      for (int j = 0; j < 4; ++j){
        int row = row0 + wr * 64 + m * 16 + kgrp * 4 + j;
        if (row < M) C[(size_t)row * Nn + col] = (_Float16)acc[m][n][j];
      }
    }
  }
  // fused alpha epilogue: this wave owns head = 2*by + wc over its 64 rows x 64 cols
  const int head = 2 * blockIdx.y + wc;
  float asv[4], adv[4];
  #pragma unroll
  for (int n = 0; n < 4; ++n){
    asv[n] = a_src[head * 64 + n * 16 + r15];
    adv[n] = a_dst[head * 64 + n * 16 + r15];
  }
  #pragma unroll
  for (int m = 0; m < 4; ++m){
    #pragma unroll
    for (int j = 0; j < 4; ++j){
      float ps = 0.f, pd = 0.f;
      #pragma unroll
      for (int n = 0; n < 4; ++n){
        float c = acc[m][n][j];
        ps += c * asv[n];
        pd += c * adv[n];
      }
      #pragma unroll
      for (int msk = 1; msk < 16; msk <<= 1){
        ps += __shfl_xor(ps, msk);
        pd += __shfl_xor(pd, msk);
      }
      int row = row0 + wr * 64 + m * 16 + kgrp * 4 + j;
      if (r15 == 0 && row < M){
        AS[(size_t)row * 8 + head] = ps;
        AD[(size_t)row * 8 + head] = pd;
      }
    }
  }
}

// ---------------- GAT aggregation, pipelined gather, fused bias+ELU ----------------
__global__ __launch_bounds__(256) void agg_f16(
    const _Float16* __restrict__ H16,
    const float* __restrict__ AS, const float* __restrict__ AD,
    const int* __restrict__ offsets, const int* __restrict__ csr_src,
    const float* __restrict__ bias, _Float16* __restrict__ O16, int N)
{
  const int wave = threadIdx.x >> 6, lane = threadIdx.x & 63;
  const int d = blockIdx.x * 4 + wave;
  if (d >= N) return;
  const int beg = offsets[d], end = offsets[d + 1];
  const int h8 = lane & 7;
  const float adv = AD[(size_t)d * 8 + h8];
  // pass A: online (max, denom) for head h8; unroll x2
  float m = -1e30f, den = 0.f;
  int sl = beg + (lane >> 3);
  for (; sl + 8 < end; sl += 16){
    int s0 = csr_src[sl], s1 = csr_src[sl + 8];
    float e0 = lrelu(AS[(size_t)s0 * 8 + h8] + adv);
    float e1 = lrelu(AS[(size_t)s1 * 8 + h8] + adv);
    float mn = fmaxf(m, fmaxf(e0, e1));
    den = den * __expf(m - mn) + __expf(e0 - mn) + __expf(e1 - mn);
    m = mn;
  }
  if (sl < end){
    int s0 = csr_src[sl];
    float e0 = lrelu(AS[(size_t)s0 * 8 + h8] + adv);
    float mn = fmaxf(m, e0);
    den = den * __expf(m - mn) + __expf(e0 - mn);
    m = mn;
  }
  #pragma unroll
  for (int msk = 8; msk < 64; msk <<= 1){
    float mo = __shfl_xor(m, msk);
    float dn = __shfl_xor(den, msk);
    float mn = fmaxf(m, mo);
    den = den * __expf(m - mn) + dn * __expf(mo - mn);
    m = mn;
  }
  const int hA = lane >> 3;
  const float dAi = 1.f / fmaxf(__shfl(den, hA), 1e-16f);
  float acc[8];
  #pragma unroll
  for (int j = 0; j < 8; ++j) acc[j] = 0.f;

  const uint4* Hv = (const uint4*)H16;   // row stride 64 uint4
  int slot = beg;
  for (; slot + 4 <= end; slot += 4){
    int s0 = csr_src[slot], s1 = csr_src[slot + 1], s2 = csr_src[slot + 2], s3 = csr_src[slot + 3];
    float p0 = AS[(size_t)s0 * 8 + h8];
    float p1 = AS[(size_t)s1 * 8 + h8];
    float p2 = AS[(size_t)s2 * 8 + h8];
    float p3 = AS[(size_t)s3 * 8 + h8];
    uint4 u0 = Hv[(size_t)s0 * 64 + lane];
    uint4 u1 = Hv[(size_t)s1 * 64 + lane];
    uint4 u2 = Hv[(size_t)s2 * 64 + lane];
    uint4 u3 = Hv[(size_t)s3 * 64 + lane];
    float al0 = __expf(lrelu(p0 + adv) - m);
    float al1 = __expf(lrelu(p1 + adv) - m);
    float al2 = __expf(lrelu(p2 + adv) - m);
    float al3 = __expf(lrelu(p3 + adv) - m);
    float a0 = __shfl(al0, hA) * dAi;
    float a1 = __shfl(al1, hA) * dAi;
    float a2 = __shfl(al2, hA) * dAi;
    float a3 = __shfl(al3, hA) * dAi;
    H8U U0, U1, U2, U3;
    U0.u = u0; U1.u = u1; U2.u = u2; U3.u = u3;
    #pragma unroll
    for (int j = 0; j < 8; ++j){
      acc[j] += a0 * (float)U0.h[j];
      acc[j] += a1 * (float)U1.h[j];
      acc[j] += a2 * (float)U2.h[j];
      acc[j] += a3 * (float)U3.h[j];
    }
  }
  for (; slot < end; ++slot){
    int s0 = csr_src[slot];
    float p0 = AS[(size_t)s0 * 8 + h8];
    uint4 u0 = Hv[(size_t)s0 * 64 + lane];
    float al0 = __expf(lrelu(p0 + adv) - m);
    float a0 = __shfl(al0, hA) * dAi;
    H8U U0; U0.u = u0;
    #pragma unroll
    for (int j = 0; j < 8; ++j) acc[j] += a0 * (float)U0.h[j];
  }
  const float4 b0 = *(const float4*)(bias + lane * 8);
  const float4 b1 = *(const float4*)(bias + lane * 8 + 4);
  acc[0] += b0.x; acc[1] += b0.y; acc[2] += b0.z; acc[3] += b0.w;
  acc[4] += b1.x; acc[5] += b1.y; acc[6] += b1.z; acc[7] += b1.w;
  H8U O;
  #pragma unroll
  for (int j = 0; j < 8; ++j) O.h[j] = (_Float16)elu1(acc[j]);
  *(uint4*)(O16 + (size_t)d * 512 + lane * 8) = O.u;
}

// ---------------- narrow GEMM: Y[M,16](f32) = X[Mpad,512](f16) @ W[512,16](f32) ----------------
__global__ __launch_bounds__(256) void gemm_n16_f16(const _Float16* __restrict__ X, const float* __restrict__ W,
                                                    float* __restrict__ Y, int M, int K){
  __shared__ float Ws[512 * 16];
  __shared__ float Xs[64][68];
  const int tid = threadIdx.x;
  for (int i = tid; i < K * 16; i += 256) Ws[i] = W[i];
  const int tx = tid & 15;
  const int ty = tid >> 4;
  const int row0 = blockIdx.x * 64;
  float acc[4] = {0.f, 0.f, 0.f, 0.f};
  for (int k0 = 0; k0 < K; k0 += 64){
    __syncthreads();
    #pragma unroll
    for (int it = 0; it < 2; ++it){
      int idx = it * 2048 + tid * 8;
      int r = idx >> 6, c = idx & 63;
      H8U U; U.u = *(const uint4*)(X + (size_t)(row0 + r) * K + k0 + c);
      float4 f0 = make_float4((float)U.h[0], (float)U.h[1], (float)U.h[2], (float)U.h[3]);
      float4 f1 = make_float4((float)U.h[4], (float)U.h[5], (float)U.h[6], (float)U.h[7]);
      *(float4*)&Xs[r][c] = f0;
      *(float4*)&Xs[r][c + 4] = f1;
    }
    __syncthreads();
    #pragma unroll
    for (int kk = 0; kk < 64; ++kk){
      float w = Ws[(k0 + kk) * 16 + tx];
      #pragma unroll
      for (int i = 0; i < 4; ++i) acc[i] += Xs[ty * 4 + i][kk] * w;
    }
  }
  #pragma unroll
  for (int i = 0; i < 4; ++i){
    int grow = row0 + ty * 4 + i;
    if (grow < M) Y[(size_t)grow * 16 + tx] = acc[i];
  }
}

// ---------------- layer-3 node coefficients (1 head, 16 ch) ----------------
__global__ __launch_bounds__(256) void alpha3_kernel(const float* __restrict__ H3,
    const float* __restrict__ a3s, const float* __restrict__ a3d,
    float* __restrict__ AS3, float* __restrict__ AD3, int N){
  const int lane = threadIdx.x & 63;
  const int wave = threadIdx.x >> 6;
  const int c = lane & 15;
  const int n = blockIdx.x * 16 + wave * 4 + (lane >> 4);
  float v = (n < N) ? H3[(size_t)n * 16 + c] : 0.f;
  float ps = v * a3s[c];
  float pd = v * a3d[c];
  #pragma unroll
  for (int msk = 1; msk < 16; msk <<= 1){ ps += __shfl_xor(ps, msk); pd += __shfl_xor(pd, msk); }
  if (c == 0 && n < N){ AS3[n] = ps; AD3[n] = pd; }
}

// ---------------- layer-3 aggregation (1 head, 16 ch) + bias + log_softmax ----------------
__global__ __launch_bounds__(256) void agg3_kernel(
    const float* __restrict__ H3,
    const float* __restrict__ AS3, const float* __restrict__ AD3,
    const int* __restrict__ offsets, const int* __restrict__ csr_src,
    const float* __restrict__ bias, float* __restrict__ Out, int N)
{
  const int wave = threadIdx.x >> 6, lane = threadIdx.x & 63;
  const int d = blockIdx.x * 4 + wave;
  if (d >= N) return;
  const int beg = offsets[d], end = offsets[d + 1];
  const float adv = AD3[d];
  float m = -1e30f, den = 0.f;
  for (int slot = beg + lane; slot < end; slot += 64){
    int s = csr_src[slot];
    float e = lrelu(AS3[s] + adv);
    float mn = fmaxf(m, e);
    den = den * __expf(m - mn) + __expf(e - mn);
    m = mn;
  }
  #pragma unroll
  for (int msk = 1; msk < 64; msk <<= 1){
    float mo = __shfl_xor(m, msk);
    float dn = __shfl_xor(den, msk);
    float mn = fmaxf(m, mo);
    den = den * __expf(m - mn) + dn * __expf(mo - mn);
    m = mn;
  }
  float denv = fmaxf(den, 1e-16f);
  const int c = lane & 15;
  float acc = 0.f;
  for (int slot = beg + (lane >> 4); slot < end; slot += 4){
    int s = csr_src[slot];
    float al = __expf(lrelu(AS3[s] + adv) - m) / denv;
    acc += al * H3[(size_t)s * 16 + c];
  }
  acc += __shfl_xor(acc, 16);
  acc += __shfl_xor(acc, 32);
  float v = acc + bias[c];
  float mm = v;
  #pragma unroll
  for (int msk = 1; msk < 16; msk <<= 1) mm = fmaxf(mm, __shfl_xor(mm, msk));
  float se = __expf(v - mm);
  #pragma unroll
  for (int msk = 1; msk < 16; msk <<= 1) se += __shfl_xor(se, msk);
  float r = v - mm - __logf(se);
  if (lane < 16) Out[(size_t)d * 16 + lane] = r;
}

extern "C" void kernel_launch(void* const* d_in, const int* in_sizes, int n_in,
                              void* d_out, int out_size, void* d_ws, size_t ws_size,
                              hipStream_t stream)
{
  const float* x   = (const float*)d_in[0];
  const int*   ei  = (const int*)d_in[1];
  const float* W1  = (const float*)d_in[2];
  const float* as1 = (const float*)d_in[3];
  const float* ad1 = (const float*)d_in[4];
  const float* b1  = (const float*)d_in[5];
  const float* W2  = (const float*)d_in[6];
  const float* as2 = (const float*)d_in[7];
  const float* ad2 = (const float*)d_in[8];
  const float* b2  = (const float*)d_in[9];
  const float* W3  = (const float*)d_in[10];
  const float* as3 = (const float*)d_in[11];
  const float* ad3 = (const float*)d_in[12];
  const float* b3  = (const float*)d_in[13];

  const int N    = in_sizes[0] / 256;
  const int E    = in_sizes[1] / 2;
  const int Et   = E + N;
  const int Mpad = (N + 127) & ~127;
  const int nb   = (N + 255) / 256;
  const int* src = ei;
  const int* dst = ei + E;

  char* base = (char*)d_ws;
  size_t off = 0;
  auto take = [&](size_t bytes) -> char* {
    char* p = base + off;
    off = (off + bytes + 255) & ~(size_t)255;
    return p;
  };
  _Float16* x16  = (_Float16*)take((size_t)Mpad * 256 * 2);
  _Float16* H16  = (_Float16*)take((size_t)Mpad * 512 * 2);
  _Float16* O16  = (_Float16*)take((size_t)Mpad * 512 * 2);
  _Float16* W1T  = (_Float16*)take((size_t)512 * 256 * 2);
  _Float16* W2T  = (_Float16*)take((size_t)512 * 512 * 2);
  float* AS   = (float*)take((size_t)N * 8 * 4);
  float* AD   = (float*)take((size_t)N * 8 * 4);
  float* H3   = (float*)take((size_t)N * 16 * 4);
  float* AS3  = (float*)take((size_t)N * 4);
  float* AD3  = (float*)take((size_t)N * 4);
  int* counts  = (int*)take((size_t)2 * N * 4);
  int* cursor  = counts + N;
  int* offsets = (int*)take((size_t)(N + 1) * 4);
  int* bsum    = (int*)take((size_t)(nb + 1) * 4);
  int* csr     = (int*)take((size_t)Et * 4);
  if (off > ws_size) return;

  hipMemsetAsync(counts, 0, (size_t)2 * N * 4, stream);
  const int tb = 256;
  count_kernel<<<(Et + tb - 1) / tb, tb, 0, stream>>>(dst, E, N, counts);
  block_sum_kernel<<<nb, 256, 0, stream>>>(counts, N, bsum);
  scan_bsum_kernel<<<1, 256, 0, stream>>>(bsum, nb, offsets, N);
  scan_within_kernel<<<nb, 256, 0, stream>>>(counts, bsum, offsets, N);
  fill_kernel<<<(Et + tb - 1) / tb, tb, 0, stream>>>(src, dst, E, N, offsets, cursor, csr);

  {
    int total = Mpad * 256, valid = N * 256;
    convert_x_f16<<<(total / 8 + tb - 1) / tb, tb, 0, stream>>>(x, x16, valid, total);
  }
  transpose_w_f16<<<dim3(256 / 32, 512 / 32), 256, 0, stream>>>(W1, W1T, 256, 512);
  transpose_w_f16<<<dim3(512 / 32, 512 / 32), 256, 0, stream>>>(W2, W2T, 512, 512);

  const int gM = Mpad / 128;
  // layer 1
  gemm_f16_mfma<<<dim3(gM, 4), 256, 0, stream>>>(x16, W1T, H16, as1, ad1, AS, AD, N, 512, 256);
  agg_f16<<<(N + 3) / 4, 256, 0, stream>>>(H16, AS, AD, offsets, csr, b1, O16, N);
  // layer 2
  gemm_f16_mfma<<<dim3(gM, 4), 256, 0, stream>>>(O16, W2T, H16, as2, ad2, AS, AD, N, 512, 512);
  agg_f16<<<(N + 3) / 4, 256, 0, stream>>>(H16, AS, AD, offsets, csr, b2, O16, N);
  // layer 3
  gemm_n16_f16<<<(N + 63) / 64, 256, 0, stream>>>(O16, W3, H3, N, 512);
  alpha3_kernel<<<(N + 15) / 16, 256, 0, stream>>>(H3, as3, ad3, AS3, AD3, N);
  agg3_kernel<<<(N + 3) / 4, 256, 0, stream>>>(H3, AS3, AD3, offsets, csr, b3, (float*)d_out, N);
}